// Round 4
// baseline (66.792 us; speedup 1.0000x reference)
//
#include <hip/hip_runtime.h>
#include <math.h>

// Problem constants: B=4, CIN=32, COUT=64, H=W=32, K=3, pad=1

typedef _Float16 half8 __attribute__((ext_vector_type(8)));
typedef float floatx4 __attribute__((ext_vector_type(4)));
typedef float float2v __attribute__((ext_vector_type(2)));

#define AL_OFF 26112  // 1632 * 16
#define SPW_OFF 52224

// R16: SINGLE kernel, no workspace, no grid barrier (R13 lesson: device-scope
// coherence is the poison — so each block is fully self-sufficient).
// B is computed on the fly: block stages its probe/outw slice (72 KB,
// coalesced) into LDS once, then each lane builds its 4 B half8-fragments
// per tap from 4 ds_read_b64 + sincos VALU (formulas bit-identical to the
// old prep kernel). Replaces: prep kernel node + inter-kernel gap + 288 KB
// per-block B reads from L2 + the 48-VGPR B register pipeline.
// LDS: sA [0,52224) | sPW [52224, 52224+73728) ; sR aliases sA[0,16384)
// behind a post-tap-loop barrier.
__global__ __launch_bounds__(512, 2) void ring_one(
    const float* __restrict__ x, const float* __restrict__ probe,
    const float* __restrict__ outw, float* __restrict__ out) {
  __shared__ __align__(16) char sMem[52224 + 73728];
  char* sA = sMem;
  float* sPW = (float*)(sMem + SPW_OFF);  // interleaved {probe,outw} per unit
  float* sR = (float*)sMem;               // epilogue reuse of sA (after barrier)

  int blk = blockIdx.x;  // (b*32 + h)*2 + oh
  int oh = blk & 1;
  int h = (blk >> 1) & 31;
  int b = blk >> 6;
  int tid = threadIdx.x;

  int lane = tid & 63;
  int wv = tid >> 6;
  int n16 = lane & 15;
  int quad = lane >> 4;
  int kg = wv >> 2;
  int xy = (wv >> 1) & 1;
  int og = wv & 1;

  // ---- stage probe/outw block slice into LDS, interleaved float2 ----
  // unit j = c*288 + ol*9 + tap (c 0..31, ol 0..31 with o = oh*32+ol, tap 0..8)
  // global idx = (c*64 + oh*32 + ol)*9 + tap = c*576 + oh*288 + (j % 288)
#pragma unroll
  for (int it = 0; it < 18; ++it) {
    int j = tid + it * 512;
    int c = j / 288;
    int rem = j - c * 288;
    int g = c * 576 + oh * 288 + rem;
    float2v pw = {probe[g], outw[g]};
    *(float2v*)(sPW + 2 * j) = pw;
  }

  // ---- A-setup (R15, proven): one unit = one (r, kchunk q, colidx), both hf
  // halves, single half8 store per var. Gather coalesced along w. LDS layout
  // byte-identical to the proven kernel; MFMA-side swizzled reads unchanged.
  {
    float xv0[4], xv1[4];
#pragma unroll
    for (int it = 0; it < 4; ++it) {
      int u = tid + it * 512;
      int colidx = u % 34;
      int t = u / 34;  // r*16 + q
      int q = t & 15;
      int r = t >> 4;
      int hs = h + r - 1;
      int wsx = colidx - 1;
      bool valid = (u < 1632) && ((unsigned)hs < 32u) && ((unsigned)wsx < 32u);
      int xi = ((b * 32 + q * 2) * 32 + ((unsigned)hs < 32u ? hs : 0)) * 32 +
               ((unsigned)wsx < 32u ? wsx : 0);
      xv0[it] = valid ? x[xi] : 0.0f;         // c = q*2   (pad -> phase 0)
      xv1[it] = valid ? x[xi + 1024] : 0.0f;  // c = q*2+1 (c stride = 32*32)
    }
#pragma unroll
    for (int it = 0; it < 4; ++it) {
      int u = tid + it * 512;
      if (u < 1632) {
        int colidx = u % 34;
        int t = u / 34;
        int q = t & 15;
        int r = t >> 4;
        int p = q ^ (colidx & 7);  // same swizzle as the MFMA-side read
        half8 hi, lo;
        float pv2[2] = {xv0[it], xv1[it]};
#pragma unroll
        for (int hf = 0; hf < 2; ++hf) {
          float s1, c1;
          __sincosf(pv2[hf], &s1, &c1);
          float c3 = c1 * fmaf(4.0f * c1, c1, -3.0f);
          float s3 = s1 * fmaf(-4.0f * s1, s1, 3.0f);
          float v4[4] = {c1, s1, c3, s3};
#pragma unroll
          for (int f = 0; f < 4; ++f) {
            _Float16 hv = (_Float16)v4[f];
            hi[hf * 4 + f] = hv;
            lo[hf * 4 + f] = (_Float16)((v4[f] - (float)hv) * 2048.0f);
          }
        }
        int ub = ((r * 34 + colidx) * 16 + p) * 16;
        *(half8*)(sA + ub) = hi;           // var 0 (hi)
        *(half8*)(sA + ub + AL_OFF) = lo;  // var 1 (lo*2048)
      }
    }
  }

  // per-lane B eval bases: e = ec*2+ehf -> c_e = (kg*8+quad+ec*4)*2+ehf
  int ol = og * 16 + n16;
  int jb0 = ((kg * 8 + quad) * 2 + 0) * 288 + ol * 9;
  int jb1 = ((kg * 8 + quad) * 2 + 1) * 288 + ol * 9;
  int jb2 = ((kg * 8 + quad + 4) * 2 + 0) * 288 + ol * 9;
  int jb3 = ((kg * 8 + quad + 4) * 2 + 1) * 288 + ol * 9;

  floatx4 acc0[2], acc1[2], acc2[2];
#pragma unroll
  for (int wt = 0; wt < 2; ++wt) {
    acc0[wt] = (floatx4){0.f, 0.f, 0.f, 0.f};  // Ah*Bh
    acc1[wt] = (floatx4){0.f, 0.f, 0.f, 0.f};  // Al*Bh
    acc2[wt] = (floatx4){0.f, 0.f, 0.f, 0.f};  // Ah*Bl
  }

  __syncthreads();  // sA + sPW visible; tap loop is barrier-free

#pragma unroll
  for (int tap = 0; tap < 9; ++tap) {
    // ---- build this tap's B fragments from staged scalars (prep formulas,
    // bit-identical products; m via wave-uniform __sinf/__cosf) ----
    half8 BH0, BH1, BL0, BL1;
#pragma unroll
    for (int e = 0; e < 4; ++e) {
      int jb = (e == 0) ? jb0 : (e == 1) ? jb1 : (e == 2) ? jb2 : jb3;
      float2v pw = *(const float2v*)(sPW + 2 * (jb + tap));
      float th = pw[0];
      float wvv = pw[1];
      float sth, cth;
      __sincosf(th, &sth, &cth);
      float m = xy ? __sinf(wvv) : __cosf(wvv);
      float c3 = cth * fmaf(4.0f * cth, cth, -3.0f);
      float s3 = sth * fmaf(-4.0f * sth, sth, 3.0f);
      float m75 = 0.75f * m, m25 = 0.25f * m;
      float v4[4] = {m75 * cth, m75 * sth, m25 * c3, m25 * s3};
      int ehf = e & 1;
#pragma unroll
      for (int f = 0; f < 4; ++f) {
        _Float16 hv = (_Float16)v4[f];
        _Float16 lv = (_Float16)((v4[f] - (float)hv) * 2048.0f);
        if (e < 2) {
          BH0[ehf * 4 + f] = hv;
          BL0[ehf * 4 + f] = lv;
        } else {
          BH1[ehf * 4 + f] = hv;
          BL1[ehf * 4 + f] = lv;
        }
      }
    }

    int dk = tap / 3;
    int l = tap - dk * 3;
#pragma unroll
    for (int wt = 0; wt < 2; ++wt) {
      int colidx = wt * 16 + n16 + l;
      int akey = colidx & 7;  // same for both wt (16 % 8 == 0)
      const char* aH = sA + (dk * 34 + colidx) * 256;
      const char* aL = aH + AL_OFF;
#pragma unroll
      for (int ksl = 0; ksl < 2; ++ksl) {
        int chunk = (kg * 2 + ksl) * 4 + quad;
        int pa = (chunk ^ akey) * 16;
        half8 Ah = *(const half8*)(aH + pa);
        half8 Al = *(const half8*)(aL + pa);
        half8 Bh = ksl ? BH1 : BH0;
        half8 Bl = ksl ? BL1 : BL0;
        acc0[wt] = __builtin_amdgcn_mfma_f32_16x16x32_f16(Ah, Bh, acc0[wt], 0, 0, 0);
        acc1[wt] = __builtin_amdgcn_mfma_f32_16x16x32_f16(Al, Bh, acc1[wt], 0, 0, 0);
        acc2[wt] = __builtin_amdgcn_mfma_f32_16x16x32_f16(Ah, Bl, acc2[wt], 0, 0, 0);
      }
    }
  }

  floatx4 finA = acc0[0] + (acc1[0] + acc2[0]) * (1.0f / 2048.0f);  // wt=0
  floatx4 finB = acc0[1] + (acc1[1] + acc2[1]) * (1.0f / 2048.0f);  // wt=1

  // ---- epilogue (R15 distributed form; sR aliases sA so barrier first) ----
  __syncthreads();  // all sA reads complete before sR overwrites it
  {
    int basei = wv * 512 + n16 * 16 + quad * 4;
    *(floatx4*)(sR + basei) = finA;
    *(floatx4*)(sR + basei + 256) = finB;
  }
  __syncthreads();
  if (tid < 256) {
    int o5 = tid >> 3;        // 0..31: o within this oh half
    int wt = (tid >> 2) & 1;  // pixel half
    int q4 = tid & 3;         // m quad
    int n16r = o5 & 15;
    int ogr = o5 >> 4;
    int sb = wt * 256 + n16r * 16 + q4 * 4;
    floatx4 ax4 = *(const floatx4*)(sR + (0 + ogr) * 512 + sb) +  // kg0,xy0
                  *(const floatx4*)(sR + (4 + ogr) * 512 + sb);   // kg1,xy0
    floatx4 ay4 = *(const floatx4*)(sR + (2 + ogr) * 512 + sb) +  // kg0,xy1
                  *(const floatx4*)(sR + (6 + ogr) * 512 + sb);   // kg1,xy1
    float4 res;
    float* rp = (float*)&res;
#pragma unroll
    for (int r = 0; r < 4; ++r) rp[r] = atan2f(ay4[r], ax4[r]);
    int o = oh * 32 + o5;
    float* dst =
        out + (((size_t)(b * 64 + o) * 32 + h) * 32 + wt * 16 + q4 * 4);
    *(float4*)dst = res;
  }
}

extern "C" void kernel_launch(void* const* d_in, const int* in_sizes, int n_in,
                              void* d_out, int out_size, void* d_ws, size_t ws_size,
                              hipStream_t stream) {
  const float* x = (const float*)d_in[0];
  const float* probe = (const float*)d_in[1];
  const float* outw = (const float*)d_in[2];
  float* out = (float*)d_out;
  (void)d_ws;
  (void)ws_size;

  ring_one<<<256, 512, 0, stream>>>(x, probe, outw, out);
}

// Round 7
// 66.729 us; speedup vs baseline: 1.0009x; 1.0009x over previous
//
#include <hip/hip_runtime.h>
#include <math.h>

// Problem constants: B=4, CIN=32, COUT=64, H=W=32, K=3, pad=1

typedef _Float16 half8 __attribute__((ext_vector_type(8)));
typedef float floatx4 __attribute__((ext_vector_type(4)));

// ---------------- workspace layout ----------------
// B_f16: [var 2][tap 9][kchunk 16][n 128][16B]  = 576 KB (L2-resident)
//   n = xy*64 + o (xy: 0=cos-weights, 1=sin-weights)
//   kchunk q holds k = q*8 + j; c = k>>2 = q*2 + (j>>2), feat = k&3
//   var 0 = hi, var 1 = lo*2048
// COALESCED for the MFMA wave read (R12). B-lo required (R9: atan2 branch cut).
// Two-kernel structure (R14): fused grid barrier poisonous (R13, +12us);
// single-kernel fusion neutral (R16) -> kernel-node count is NOT the cost.
#define B_TAP_STRIDE (16 * 128 * 16)    // 32768
#define B_VSTRIDE (9u * 16 * 128 * 16)  // 294912

#define AL_OFF 26112  // 1632 * 16

__global__ __launch_bounds__(256) void ring_prep_b(
    const float* __restrict__ probe, const float* __restrict__ outw,
    char* __restrict__ Bg) {
  int i = blockIdx.x * 256 + threadIdx.x;  // 18432 threads = 72 blocks
  int q = i & 15;                          // kchunk (no XOR)
  int n = (i >> 4) & 127;
  int tap = i >> 11;
  int o = n & 63;
  int xy = n >> 6;
  half8 hi, lo;
#pragma unroll
  for (int hf = 0; hf < 2; ++hf) {
    int c = q * 2 + hf;
    int idx = (c * 64 + o) * 9 + tap;  // ((c*COUT + o)*3 + k)*3 + l
    float th = probe[idx];
    float wvv = outw[idx];
    float sth, cth, sw, cw;
    __sincosf(th, &sth, &cth);
    __sincosf(wvv, &sw, &cw);
    float c3 = cth * fmaf(4.0f * cth, cth, -3.0f);
    float s3 = sth * fmaf(-4.0f * sth, sth, 3.0f);
    float m = xy ? sw : cw;
    float v4[4] = {0.75f * m * cth, 0.75f * m * sth, 0.25f * m * c3,
                   0.25f * m * s3};
#pragma unroll
    for (int f = 0; f < 4; ++f) {
      _Float16 hv = (_Float16)v4[f];
      hi[hf * 4 + f] = hv;
      lo[hf * 4 + f] = (_Float16)((v4[f] - (float)hv) * 2048.0f);
    }
  }
  size_t off = (((size_t)tap * 16 + q) * 128 + n) * 16;
  *(half8*)(Bg + off) = hi;
  *(half8*)(Bg + off + B_VSTRIDE) = lo;
}

// R17: 16-wave blocks (1024 thr) = 4 waves/SIMD (was 2) — occupancy is the
// last untested multi-us lever; the kernel is a chain of latency phases and
// per-wave issue work is tiny. Wave roles (wt, kg, xy, og): wt promoted from
// in-wave loop to wave role. Total MFMA, B L2 traffic (wt-twins hit L1),
// LDS bytes, and arithmetic UNCHANGED. B pipeline 2-deep (32 VGPR) to fit
// the mandatory <=128 VGPR for 16-wave residency.
#define BLOAD2(dst, base)                    \
  do {                                       \
    dst##0 = *(const half8*)((base));        \
    dst##1 = *(const half8*)((base) + 8192); \
  } while (0)

__global__ __launch_bounds__(1024) void ring_mfma(
    const float* __restrict__ x, const char* __restrict__ Bg,
    float* __restrict__ out) {
  __shared__ __align__(16) char sA[52224];
  __shared__ __align__(16) float sR[4096];  // [wv 16][n16 16][m 16]

  int blk = blockIdx.x;  // (b*32 + h)*2 + oh
  int oh = blk & 1;
  int h = (blk >> 1) & 31;
  int b = blk >> 6;
  int tid = threadIdx.x;

  int lane = tid & 63;
  int wv = tid >> 6;       // 0..15
  int n16 = lane & 15;
  int quad = lane >> 4;
  int og = wv & 1;
  int xy = (wv >> 1) & 1;
  int kg = (wv >> 2) & 1;
  int wt = wv >> 3;

  int n_global = xy * 64 + oh * 32 + og * 16 + n16;
  // this wave's kchunks: kg*8 + {quad, quad+4}
  const char* bLane = Bg + (kg * 8 + quad) * 2048 + (size_t)n_global * 16;

  // ---- 2-deep B pipeline: prefetch tap 0 (in flight across A-setup) ----
  half8 BcH0, BcH1, BcL0, BcL1;  // tap t
  half8 BnH0, BnH1, BnL0, BnL1;  // tap t+1
  BLOAD2(BcH, bLane);
  BLOAD2(BcL, bLane + B_VSTRIDE);

  // ---- A-setup (R15, proven): one unit = (r, kchunk q, colidx), both hf
  // halves, single half8 store per var; gather coalesced along w. LDS bytes
  // byte-identical to the proven layout; MFMA-side swizzled reads unchanged.
  {
    float xv0[2], xv1[2];
#pragma unroll
    for (int it = 0; it < 2; ++it) {
      int u = tid + it * 1024;
      int colidx = u % 34;
      int t = u / 34;  // r*16 + q
      int q = t & 15;
      int r = t >> 4;
      int hs = h + r - 1;
      int wsx = colidx - 1;
      bool valid = (u < 1632) && ((unsigned)hs < 32u) && ((unsigned)wsx < 32u);
      int xi = ((b * 32 + q * 2) * 32 + ((unsigned)hs < 32u ? hs : 0)) * 32 +
               ((unsigned)wsx < 32u ? wsx : 0);
      xv0[it] = valid ? x[xi] : 0.0f;         // c = q*2   (pad -> phase 0)
      xv1[it] = valid ? x[xi + 1024] : 0.0f;  // c = q*2+1 (c stride = 32*32)
    }
#pragma unroll
    for (int it = 0; it < 2; ++it) {
      int u = tid + it * 1024;
      if (u < 1632) {
        int colidx = u % 34;
        int t = u / 34;
        int q = t & 15;
        int r = t >> 4;
        int p = q ^ (colidx & 7);  // same swizzle as the MFMA-side read
        half8 hi, lo;
        float pv2[2] = {xv0[it], xv1[it]};
#pragma unroll
        for (int hf = 0; hf < 2; ++hf) {
          float s1, c1;
          __sincosf(pv2[hf], &s1, &c1);
          float c3 = c1 * fmaf(4.0f * c1, c1, -3.0f);
          float s3 = s1 * fmaf(-4.0f * s1, s1, 3.0f);
          float v4[4] = {c1, s1, c3, s3};
#pragma unroll
          for (int f = 0; f < 4; ++f) {
            _Float16 hv = (_Float16)v4[f];
            hi[hf * 4 + f] = hv;
            lo[hf * 4 + f] = (_Float16)((v4[f] - (float)hv) * 2048.0f);
          }
        }
        int ub = ((r * 34 + colidx) * 16 + p) * 16;
        *(half8*)(sA + ub) = hi;           // var 0 (hi)
        *(half8*)(sA + ub + AL_OFF) = lo;  // var 1 (lo*2048)
      }
    }
  }

  floatx4 acc0 = {0.f, 0.f, 0.f, 0.f};  // Ah*Bh
  floatx4 acc1 = {0.f, 0.f, 0.f, 0.f};  // Al*Bh
  floatx4 acc2 = {0.f, 0.f, 0.f, 0.f};  // Ah*Bl

  __syncthreads();  // A tile visible; tap loop is barrier-free

#pragma unroll
  for (int tap = 0; tap < 9; ++tap) {
    // prefetch tap+1's B (hi+lo) — one tap of L2-latency cover + 4-wave TLP
    if (tap < 8) {
      const char* bt = bLane + (size_t)(tap + 1) * B_TAP_STRIDE;
      BLOAD2(BnH, bt);
      BLOAD2(BnL, bt + B_VSTRIDE);
    }

    int dk = tap / 3;
    int l = tap - dk * 3;
    int colidx = wt * 16 + n16 + l;
    int akey = colidx & 7;
    const char* aH = sA + (dk * 34 + colidx) * 256;
    const char* aL = aH + AL_OFF;
#pragma unroll
    for (int ksl = 0; ksl < 2; ++ksl) {
      int chunk = (kg * 2 + ksl) * 4 + quad;
      int pa = (chunk ^ akey) * 16;
      half8 Ah = *(const half8*)(aH + pa);
      half8 Al = *(const half8*)(aL + pa);
      half8 Bh = ksl ? BcH1 : BcH0;
      half8 Bl = ksl ? BcL1 : BcL0;
      acc0 = __builtin_amdgcn_mfma_f32_16x16x32_f16(Ah, Bh, acc0, 0, 0, 0);
      acc1 = __builtin_amdgcn_mfma_f32_16x16x32_f16(Al, Bh, acc1, 0, 0, 0);
      acc2 = __builtin_amdgcn_mfma_f32_16x16x32_f16(Ah, Bl, acc2, 0, 0, 0);
    }
    // rotate (fully unrolled -> register renaming)
    BcH0 = BnH0; BcH1 = BnH1; BcL0 = BnL0; BcL1 = BnL1;
  }

  floatx4 fin = acc0 + (acc1 + acc2) * (1.0f / 2048.0f);

  // ---- epilogue: all 16 waves post partials; 1024 threads each combine
  // (kg-sum, xy handoff), one atan2, one coalesced scalar store ----
  {
    int basei = wv * 256 + n16 * 16 + quad * 4;
    *(floatx4*)(sR + basei) = fin;
  }
  __syncthreads();
  {
    int o5 = tid >> 5;   // 0..31: o within this oh half (og*16 + n16)
    int w5 = tid & 31;   // output w = wt*16 + m
    int ogr = o5 >> 4;
    int n16r = o5 & 15;
    int wtr = w5 >> 4;
    int mr = w5 & 15;
    int sb = n16r * 16 + mr;
    float ax = sR[(wtr * 8 + 0 + ogr) * 256 + sb] +   // kg0, xy0
               sR[(wtr * 8 + 4 + ogr) * 256 + sb];    // kg1, xy0
    float ay = sR[(wtr * 8 + 2 + ogr) * 256 + sb] +   // kg0, xy1
               sR[(wtr * 8 + 6 + ogr) * 256 + sb];    // kg1, xy1
    float res = atan2f(ay, ax);
    out[(((size_t)(b * 64 + oh * 32 + o5) * 32 + h) * 32) + w5] = res;
  }
}

extern "C" void kernel_launch(void* const* d_in, const int* in_sizes, int n_in,
                              void* d_out, int out_size, void* d_ws, size_t ws_size,
                              hipStream_t stream) {
  const float* x = (const float*)d_in[0];
  const float* probe = (const float*)d_in[1];
  const float* outw = (const float*)d_in[2];
  char* Bg = (char*)d_ws;
  float* out = (float*)d_out;

  ring_prep_b<<<72, 256, 0, stream>>>(probe, outw, Bg);
  ring_mfma<<<256, 1024, 0, stream>>>(x, Bg, out);
}